// Round 7
// baseline (200.910 us; speedup 1.0000x reference)
//
#include <hip/hip_runtime.h>
#include <hip/hip_bf16.h>

typedef __bf16 bf16x8 __attribute__((ext_vector_type(8)));
typedef __bf16 bf16x4 __attribute__((ext_vector_type(4)));
typedef float f32x4 __attribute__((ext_vector_type(4)));

#define S_LEN 4096
#define DDIM  1024

#define MFMA __builtin_amdgcn_mfma_f32_16x16x32_bf16

#define BAR() do { asm volatile("" ::: "memory"); __builtin_amdgcn_s_barrier(); asm volatile("" ::: "memory"); } while (0)
#define VM6() asm volatile("s_waitcnt vmcnt(6)" ::: "memory")
#define VM4() asm volatile("s_waitcnt vmcnt(4)" ::: "memory")
#define VM2() asm volatile("s_waitcnt vmcnt(2)" ::: "memory")
#define VM0() asm volatile("s_waitcnt vmcnt(0)" ::: "memory")
#define LGKM0() asm volatile("s_waitcnt lgkmcnt(0)" ::: "memory")

__device__ __forceinline__ void gl_lds16(const __bf16* g, __bf16* l)
{
    __builtin_amdgcn_global_load_lds(
        (const __attribute__((address_space(1))) void*)g,
        (__attribute__((address_space(3))) void*)l, 16, 0, 0);
}

// ---------------- prep: q/k -> bf16 hi/lo planes (+ scale gather) ----------
__global__ void prep_hilo(const float* __restrict__ q, const float* __restrict__ kk,
                          __bf16* __restrict__ qh, __bf16* __restrict__ ql,
                          __bf16* __restrict__ kh, __bf16* __restrict__ kl,
                          float* __restrict__ scale)
{
    const int gid = blockIdx.x * blockDim.x + threadIdx.x;
    if (gid < S_LEN) scale[gid] = q[((size_t)(gid >> 10) << 20) + (gid & 1023)];

    const int n8 = (S_LEN * DDIM) / 8;
    for (int i = gid; i < n8; i += gridDim.x * blockDim.x) {
        float4 a = *(const float4*)(q + (size_t)i * 8);
        float4 b = *(const float4*)(q + (size_t)i * 8 + 4);
        float va[8] = {a.x, a.y, a.z, a.w, b.x, b.y, b.z, b.w};
        bf16x8 h, l;
#pragma unroll
        for (int j = 0; j < 8; ++j) {
            __bf16 hh = (__bf16)va[j];
            h[j] = hh;
            l[j] = (__bf16)(va[j] - (float)hh);
        }
        *(bf16x8*)(qh + (size_t)i * 8) = h;
        *(bf16x8*)(ql + (size_t)i * 8) = l;

        a = *(const float4*)(kk + (size_t)i * 8);
        b = *(const float4*)(kk + (size_t)i * 8 + 4);
        float vb[8] = {a.x, a.y, a.z, a.w, b.x, b.y, b.z, b.w};
#pragma unroll
        for (int j = 0; j < 8; ++j) {
            __bf16 hh = (__bf16)vb[j];
            h[j] = hh;
            l[j] = (__bf16)(vb[j] - (float)hh);
        }
        *(bf16x8*)(kh + (size_t)i * 8) = h;
        *(bf16x8*)(kl + (size_t)i * 8) = l;
    }
}

// ---------------- prep: V (S x DV) -> V^T bf16 (DV x S) ----------------
__global__ void prep_vt(const float* __restrict__ v, __bf16* __restrict__ vt)
{
    __shared__ float tile[32][33];
    const int t0 = blockIdx.x * 32;
    const int d0 = blockIdx.y * 32;
    const int tx = threadIdx.x & 31;
    const int ty = threadIdx.x >> 5;
#pragma unroll
    for (int i = 0; i < 32; i += 8)
        tile[ty + i][tx] = v[(size_t)(t0 + ty + i) * DDIM + d0 + tx];
    __syncthreads();
#pragma unroll
    for (int i = 0; i < 32; i += 8)
        vt[(size_t)(d0 + ty + i) * S_LEN + t0 + tx] = (__bf16)tile[tx][ty + i];
}

// =====================================================================
// G1: S = (Q . K^T) * colscale  (3-term bf16 hi/lo split), 8-phase 256^2
//     epilogue also emits per-(256-col-tile) row stats (M, L)
// =====================================================================
__device__ __forceinline__ const __bf16* selA(const __bf16* qh, const __bf16* ql, int ps)
{ return ps == 1 ? ql : qh; }
__device__ __forceinline__ const __bf16* selB(const __bf16* kh, const __bf16* kl, int ps)
{ return ps == 2 ? kl : kh; }

template<int BUF, int RG>
__device__ __forceinline__ void stageG1(__bf16 (&lds)[2][4][8192], const __bf16* pl,
                                        int base, int koff, int w, int lane)
{
#pragma unroll
    for (int j = 0; j < 2; ++j) {
        const int ubase = (2 * w + j) * 64;
        const int u = ubase + lane;
        const int r = u >> 3, cu = u & 7;
        int grow;
        if (RG < 2) grow = base + ((r >> 6) << 7) + ((RG & 1) << 6) + (r & 63);
        else        grow = base + ((r >> 5) << 6) + ((RG & 1) << 5) + (r & 31);
        const __bf16* src = pl + (size_t)grow * DDIM + koff + ((cu ^ (r & 7)) << 3);
        gl_lds16(src, &lds[BUF][RG][0] + ubase * 8);
    }
}

template<int BUF, int MH>
__device__ __forceinline__ void rdA(bf16x8 (&a)[4][2], const __bf16 (&lds)[2][4][8192],
                                    int wr, int arow, int aoct)
{
#pragma unroll
    for (int mi = 0; mi < 4; ++mi)
#pragma unroll
        for (int ks = 0; ks < 2; ++ks) {
            const int lr = wr * 64 + mi * 16 + arow;
            const int cc = ks * 4 + aoct;
            a[mi][ks] = *(const bf16x8*)((const char*)&lds[BUF][MH][0]
                            + lr * 128 + ((cc ^ (lr & 7)) << 4));
        }
}

template<int BUF, int NH>
__device__ __forceinline__ void rdB(bf16x8 (&b)[2][2], const __bf16 (&lds)[2][4][8192],
                                    int wc, int arow, int aoct)
{
#pragma unroll
    for (int ni = 0; ni < 2; ++ni)
#pragma unroll
        for (int ks = 0; ks < 2; ++ks) {
            const int lr = wc * 32 + ni * 16 + arow;
            const int cc = ks * 4 + aoct;
            b[ni][ks] = *(const bf16x8*)((const char*)&lds[BUF][2 + NH][0]
                            + lr * 128 + ((cc ^ (lr & 7)) << 4));
        }
}

#define QMFMA(MH, NH, bb) \
    _Pragma("unroll") for (int ks = 0; ks < 2; ++ks) \
    _Pragma("unroll") for (int mi = 0; mi < 4; ++mi) \
    _Pragma("unroll") for (int ni = 0; ni < 2; ++ni) \
        acc[(MH)*4 + mi][(NH)*2 + ni] = MFMA(a[mi][ks], bb[ni][ks], acc[(MH)*4 + mi][(NH)*2 + ni], 0, 0, 0);

__global__ __launch_bounds__(512, 2) void gemm_qk(
    const __bf16* __restrict__ qh, const __bf16* __restrict__ ql,
    const __bf16* __restrict__ kh, const __bf16* __restrict__ kl,
    const float* __restrict__ scale, float* __restrict__ Sout,
    float2* __restrict__ part)
{
    __shared__ __align__(16) __bf16 lds[2][4][8192];   // 128 KB

    const int tid = threadIdx.x;
    const int w = tid >> 6, lane = tid & 63;
    const int arow = lane & 15, aoct = lane >> 4;
    const int wr = w >> 2, wc = w & 3;
    const int nb = (blockIdx.x & 7) * 32 + (blockIdx.x >> 3);
    const int m0 = (nb & 15) * 256, n0 = (nb >> 4) * 256;

    f32x4 acc[8][4];
#pragma unroll
    for (int i = 0; i < 8; ++i)
#pragma unroll
        for (int j = 0; j < 4; ++j) acc[i][j] = (f32x4){0.f, 0.f, 0.f, 0.f};

    stageG1<0, 0>(lds, selA(qh, ql, 0), m0, 0, w, lane);
    stageG1<0, 1>(lds, selA(qh, ql, 0), m0, 0, w, lane);
    stageG1<0, 2>(lds, selB(kh, kl, 0), n0, 0, w, lane);
    stageG1<0, 3>(lds, selB(kh, kl, 0), n0, 0, w, lane);
    stageG1<1, 0>(lds, selA(qh, ql, 0), m0, 64, w, lane);
    stageG1<1, 2>(lds, selB(kh, kl, 0), n0, 64, w, lane);
    stageG1<1, 3>(lds, selB(kh, kl, 0), n0, 64, w, lane);
    VM6(); BAR();

    for (int it = 0; it < 24; ++it) {
        const int t0 = 2 * it, t1 = 2 * it + 1;
        const bool last = (it == 23);
        const int ps1 = t1 >> 4, ko1 = (t1 & 15) << 6;
        const int ps2 = (t0 + 2) >> 4, ko2 = ((t0 + 2) & 15) << 6;
        const int ps3 = (t1 + 2) >> 4, ko3 = ((t1 + 2) & 15) << 6;
        bf16x8 a[4][2], b0[2][2], b1[2][2];

        rdA<0, 0>(a, lds, wr, arow, aoct);
        rdB<0, 0>(b0, lds, wc, arow, aoct);
        stageG1<1, 1>(lds, selA(qh, ql, ps1), m0, ko1, w, lane);
        BAR();
        __builtin_amdgcn_s_setprio(1); QMFMA(0, 0, b0); __builtin_amdgcn_s_setprio(0);
        BAR();
        rdB<0, 1>(b1, lds, wc, arow, aoct);
        if (!last) stageG1<0, 0>(lds, selA(qh, ql, ps2), m0, ko2, w, lane);
        BAR();
        __builtin_amdgcn_s_setprio(1); QMFMA(0, 1, b1); __builtin_amdgcn_s_setprio(0);
        BAR();
        rdA<0, 1>(a, lds, wr, arow, aoct);
        if (!last) stageG1<0, 2>(lds, selB(kh, kl, ps2), n0, ko2, w, lane);
        BAR();
        __builtin_amdgcn_s_setprio(1); QMFMA(1, 0, b0); __builtin_amdgcn_s_setprio(0);
        BAR();
        if (!last) stageG1<0, 3>(lds, selB(kh, kl, ps2), n0, ko2, w, lane);
        if (last) { VM0(); } else { VM6(); }
        BAR();
        __builtin_amdgcn_s_setprio(1); QMFMA(1, 1, b1); __builtin_amdgcn_s_setprio(0);
        BAR();
        rdA<1, 0>(a, lds, wr, arow, aoct);
        rdB<1, 0>(b0, lds, wc, arow, aoct);
        if (!last) stageG1<0, 1>(lds, selA(qh, ql, ps2), m0, ko2, w, lane);
        BAR();
        __builtin_amdgcn_s_setprio(1); QMFMA(0, 0, b0); __builtin_amdgcn_s_setprio(0);
        BAR();
        rdB<1, 1>(b1, lds, wc, arow, aoct);
        if (!last) stageG1<1, 0>(lds, selA(qh, ql, ps3), m0, ko3, w, lane);
        BAR();
        __builtin_amdgcn_s_setprio(1); QMFMA(0, 1, b1); __builtin_amdgcn_s_setprio(0);
        BAR();
        rdA<1, 1>(a, lds, wr, arow, aoct);
        if (!last) stageG1<1, 2>(lds, selB(kh, kl, ps3), n0, ko3, w, lane);
        BAR();
        __builtin_amdgcn_s_setprio(1); QMFMA(1, 0, b0); __builtin_amdgcn_s_setprio(0);
        BAR();
        if (!last) stageG1<1, 3>(lds, selB(kh, kl, ps3), n0, ko3, w, lane);
        if (last) { VM0(); } else { VM6(); }
        BAR();
        __builtin_amdgcn_s_setprio(1); QMFMA(1, 1, b1); __builtin_amdgcn_s_setprio(0);
        BAR();
    }

    // epilogue: scale, per-tile row stats (M, L), write fp32 S
    const int nbase = n0 + wc * 64;
    float sc[4];
#pragma unroll
    for (int ni = 0; ni < 4; ++ni) sc[ni] = scale[nbase + ni * 16 + arow];

    float2* sst = (float2*)&lds[0][0][0];   // [256 rows][4 wc]
    __syncthreads();                        // main-loop LDS life over

#pragma unroll
    for (int mi = 0; mi < 8; ++mi) {
#pragma unroll
        for (int ni = 0; ni < 4; ++ni)
#pragma unroll
            for (int ii = 0; ii < 4; ++ii)
                acc[mi][ni][ii] *= sc[ni];
#pragma unroll
        for (int ii = 0; ii < 4; ++ii) {
            float m = fmaxf(fmaxf(acc[mi][0][ii], acc[mi][1][ii]),
                            fmaxf(acc[mi][2][ii], acc[mi][3][ii]));
#pragma unroll
            for (int sh = 8; sh >= 1; sh >>= 1) m = fmaxf(m, __shfl_xor(m, sh));
            float s = 0.f;
#pragma unroll
            for (int ni = 0; ni < 4; ++ni) s += __expf(acc[mi][ni][ii] - m);
#pragma unroll
            for (int sh = 8; sh >= 1; sh >>= 1) s += __shfl_xor(s, sh);
            if (arow == 0)
                sst[(wr * 128 + mi * 16 + aoct * 4 + ii) * 4 + wc] = make_float2(m, s);
        }
#pragma unroll
        for (int ni = 0; ni < 4; ++ni)
#pragma unroll
            for (int ii = 0; ii < 4; ++ii) {
                const int m = m0 + wr * 128 + mi * 16 + aoct * 4 + ii;
                Sout[(size_t)m * S_LEN + nbase + ni * 16 + arow] = acc[mi][ni][ii];
            }
    }
    __syncthreads();
    if (tid < 256) {
        float2 s0 = sst[tid * 4 + 0], s1 = sst[tid * 4 + 1];
        float2 s2 = sst[tid * 4 + 2], s3 = sst[tid * 4 + 3];
        float M = fmaxf(fmaxf(s0.x, s1.x), fmaxf(s2.x, s3.x));
        float L = s0.y * __expf(s0.x - M) + s1.y * __expf(s1.x - M)
                + s2.y * __expf(s2.x - M) + s3.y * __expf(s3.x - M);
        part[(size_t)(n0 >> 8) * S_LEN + m0 + tid] = make_float2(M, L);
    }
}

// ---------------- combine per-tile stats -> (M, 1/L) per row ----------
__global__ void combine_stats(const float2* __restrict__ part, float2* __restrict__ fin)
{
    const int r = blockIdx.x * 256 + threadIdx.x;
    float M = -3e38f;
#pragma unroll
    for (int t = 0; t < 16; ++t) M = fmaxf(M, part[(size_t)t * S_LEN + r].x);
    float L = 0.f;
#pragma unroll
    for (int t = 0; t < 16; ++t) {
        float2 p = part[(size_t)t * S_LEN + r];
        L += p.y * __expf(p.x - M);
    }
    fin[r] = make_float2(M, 1.f / L);
}

// =====================================================================
// G2: O = softmax-finish(S) . V   fused:
//   A-path: reg-stage S fp32 -> exp(x-M) -> bf16 -> swizzled ds_write (T14)
//   V-path: gl_lds direct; 2-buffer, two barriers/iter, counted vmcnt.
//   P unnormalized (<=1); 1/L folded into epilogue.
// =====================================================================
__global__ __launch_bounds__(512, 1) void gemm_pv(const float* __restrict__ S,
                                                  const __bf16* __restrict__ vt,
                                                  const float2* __restrict__ fin,
                                                  float* __restrict__ out)
{
    __shared__ __align__(16) __bf16 lds[2][2][8192];   // [buf][A|V][128x64]

    const int tid = threadIdx.x;
    const int w = tid >> 6, lane = tid & 63;
    const int arow = lane & 15, aoct = lane >> 4;
    const int wr = w >> 2, wc = w & 3;                  // 2M x 4N waves
    const int nb = (blockIdx.x & 7) * 32 + (blockIdx.x >> 3);
    const int m0 = (nb & 31) * 128, n0 = (nb >> 5) * 128;

    // per-thread staging coords (fixed across t)
    int rr[2], kof[2];
    float Mrow[2];
#pragma unroll
    for (int j = 0; j < 2; ++j) {
        const int u = (2 * w + j) * 64 + lane;
        rr[j] = u >> 3;
        kof[j] = ((u & 7) ^ (rr[j] & 7)) * 8;
        Mrow[j] = fin[m0 + rr[j]].x;
    }

    f32x4 acc[4][2];
#pragma unroll
    for (int i = 0; i < 4; ++i)
#pragma unroll
        for (int j = 0; j < 2; ++j) acc[i][j] = (f32x4){0.f, 0.f, 0.f, 0.f};

    float4 ar[2][2];
    bf16x8 pb[2];

#define LOADA(t) do { _Pragma("unroll") for (int j = 0; j < 2; ++j) { \
        const float* p_ = S + (size_t)(m0 + rr[j]) * S_LEN + (t) * 64 + kof[j]; \
        ar[j][0] = *(const float4*)p_; ar[j][1] = *(const float4*)(p_ + 4); } } while (0)
#define TRANS() do { _Pragma("unroll") for (int j = 0; j < 2; ++j) { \
        pb[j][0] = (__bf16)__expf(ar[j][0].x - Mrow[j]); \
        pb[j][1] = (__bf16)__expf(ar[j][0].y - Mrow[j]); \
        pb[j][2] = (__bf16)__expf(ar[j][0].z - Mrow[j]); \
        pb[j][3] = (__bf16)__expf(ar[j][0].w - Mrow[j]); \
        pb[j][4] = (__bf16)__expf(ar[j][1].x - Mrow[j]); \
        pb[j][5] = (__bf16)__expf(ar[j][1].y - Mrow[j]); \
        pb[j][6] = (__bf16)__expf(ar[j][1].z - Mrow[j]); \
        pb[j][7] = (__bf16)__expf(ar[j][1].w - Mrow[j]); } } while (0)
#define WRITEA(buf) do { _Pragma("unroll") for (int j = 0; j < 2; ++j) \
        *(bf16x8*)(&lds[buf][0][0] + ((2 * w + j) * 64 + lane) * 8) = pb[j]; } while (0)
#define STAGEV(buf, t) do { _Pragma("unroll") for (int j = 0; j < 2; ++j) { \
        const int ub_ = (2 * w + j) * 64; \
        gl_lds16(vt + (size_t)(n0 + rr[j]) * S_LEN + (t) * 64 + kof[j], \
                 &lds[buf][1][0] + ub_ * 8); } } while (0)

    // prologue: tile0 complete in lds[0]; A(1) in regs; V(1) -> lds[1]
    LOADA(0); STAGEV(0, 0);
    VM0();
    TRANS(); WRITEA(0);
    LOADA(1);
    LGKM0(); BAR();
    STAGEV(1, 1);

    for (int t = 0; t < 64; ++t) {
        const int cur = t & 1, nxt = cur ^ 1;
        const char* pa = (const char*)&lds[cur][0][0];
        const char* pbv = (const char*)&lds[cur][1][0];
        bf16x8 a[4][2], b[2][2];
#pragma unroll
        for (int mi = 0; mi < 4; ++mi)
#pragma unroll
            for (int ks = 0; ks < 2; ++ks) {
                const int lr = wr * 64 + mi * 16 + arow;
                const int cc = ks * 4 + aoct;
                a[mi][ks] = *(const bf16x8*)(pa + lr * 128 + ((cc ^ (lr & 7)) << 4));
            }
#pragma unroll
        for (int ni = 0; ni < 2; ++ni)
#pragma unroll
            for (int ks = 0; ks < 2; ++ks) {
                const int lr = wc * 32 + ni * 16 + arow;
                const int cc = ks * 4 + aoct;
                b[ni][ks] = *(const bf16x8*)(pbv + lr * 128 + ((cc ^ (lr & 7)) << 4));
            }
        if (t < 63) { VM2(); TRANS(); }
        BAR();                                   // (1) nxt.A write-safe
        if (t < 63) WRITEA(nxt);
        if (t < 62) LOADA(t + 2);
        __builtin_amdgcn_s_setprio(1);
#pragma unroll
        for (int ks = 0; ks < 2; ++ks)
#pragma unroll
            for (int mi = 0; mi < 4; ++mi)
#pragma unroll
                for (int ni = 0; ni < 2; ++ni)
                    acc[mi][ni] = MFMA(a[mi][ks], b[ni][ks], acc[mi][ni], 0, 0, 0);
        __builtin_amdgcn_s_setprio(0);
        __builtin_amdgcn_sched_barrier(0);       // pin MFMA cluster (rule 18)
        LGKM0();                                 // ds_writes visible
        if (t < 62) { VM4(); } else { VM0(); }   // V(t+1) landed
        BAR();                                   // (2) cur reads done block-wide
        if (t < 62) STAGEV(cur, t + 2);
    }

    // epilogue: normalize by 1/L, store fp32
#pragma unroll
    for (int mi = 0; mi < 4; ++mi)
#pragma unroll
        for (int ii = 0; ii < 4; ++ii) {
            const int m = m0 + wr * 64 + mi * 16 + aoct * 4 + ii;
            const float invl = fin[m].y;
#pragma unroll
            for (int ni = 0; ni < 2; ++ni) {
                const int n = n0 + wc * 32 + ni * 16 + arow;
                out[(size_t)m * DDIM + n] = acc[mi][ni][ii] * invl;
            }
        }
#undef LOADA
#undef TRANS
#undef WRITEA
#undef STAGEV
}

extern "C" void kernel_launch(void* const* d_in, const int* in_sizes, int n_in,
                              void* d_out, int out_size, void* d_ws, size_t ws_size,
                              hipStream_t stream)
{
    const float* q = (const float*)d_in[0];
    const float* k = (const float*)d_in[1];
    const float* v = (const float*)d_in[2];
    float* out = (float*)d_out;

    const size_t PLANE = (size_t)S_LEN * DDIM * sizeof(__bf16);        // 8 MiB
    const size_t SOFF  = 5 * PLANE + 64 * 1024;
    const size_t SBYTES = (size_t)S_LEN * S_LEN * sizeof(float);       // 64 MiB
    const size_t POFF  = SOFF + SBYTES;
    const size_t FOFF  = POFF + 16 * (size_t)S_LEN * sizeof(float2);   // +512 KiB
    const size_t NEEDED = FOFF + (size_t)S_LEN * sizeof(float2);
    if (ws_size < NEEDED) return;  // fail visibly (poisoned output)

    char* ws = (char*)d_ws;
    __bf16* qh = (__bf16*)(ws);
    __bf16* ql = (__bf16*)(ws + PLANE);
    __bf16* kh = (__bf16*)(ws + 2 * PLANE);
    __bf16* kl = (__bf16*)(ws + 3 * PLANE);
    __bf16* vt = (__bf16*)(ws + 4 * PLANE);
    float* scale = (float*)(ws + 5 * PLANE);
    float* Smat = (float*)(ws + SOFF);
    float2* part = (float2*)(ws + POFF);
    float2* fin = (float2*)(ws + FOFF);

    prep_hilo<<<dim3(1024), dim3(256), 0, stream>>>(q, k, qh, ql, kh, kl, scale);
    prep_vt<<<dim3(S_LEN / 32, DDIM / 32), dim3(256), 0, stream>>>(v, vt);
    gemm_qk<<<dim3(256), dim3(512), 0, stream>>>(qh, ql, kh, kl, scale, Smat, part);
    combine_stats<<<dim3(S_LEN / 256), dim3(256), 0, stream>>>(part, fin);
    gemm_pv<<<dim3(256), dim3(512), 0, stream>>>(Smat, vt, fin, out);
}

// Round 9
// 162.750 us; speedup vs baseline: 1.2345x; 1.2345x over previous
//
#include <hip/hip_runtime.h>
#include <hip/hip_bf16.h>

typedef __bf16 bf16x8 __attribute__((ext_vector_type(8)));
typedef __bf16 bf16x4 __attribute__((ext_vector_type(4)));
typedef float f32x4 __attribute__((ext_vector_type(4)));

#define S_LEN 4096
#define DDIM  1024

#define MFMA __builtin_amdgcn_mfma_f32_16x16x32_bf16

#define BAR() do { asm volatile("" ::: "memory"); __builtin_amdgcn_s_barrier(); asm volatile("" ::: "memory"); } while (0)
#define VM8() asm volatile("s_waitcnt vmcnt(8)" ::: "memory")
#define VM6() asm volatile("s_waitcnt vmcnt(6)" ::: "memory")
#define VM4() asm volatile("s_waitcnt vmcnt(4)" ::: "memory")
#define VM0() asm volatile("s_waitcnt vmcnt(0)" ::: "memory")

__device__ __forceinline__ void gl_lds16(const __bf16* g, __bf16* l)
{
    __builtin_amdgcn_global_load_lds(
        (const __attribute__((address_space(1))) void*)g,
        (__attribute__((address_space(3))) void*)l, 16, 0, 0);
}

// ---------------- merged prep: hilo+scale (blocks 0..1023) | vt (1024..5119) ----
__global__ void prep_all(const float* __restrict__ q, const float* __restrict__ kk,
                         const float* __restrict__ v,
                         __bf16* __restrict__ qh, __bf16* __restrict__ ql,
                         __bf16* __restrict__ kh, __bf16* __restrict__ kl,
                         __bf16* __restrict__ vt, float* __restrict__ scale)
{
    __shared__ float tile[32][33];
    const int bid = blockIdx.x;
    if (bid < 1024) {
        const int gid = bid * 256 + threadIdx.x;
        if (gid < S_LEN) scale[gid] = q[((size_t)(gid >> 10) << 20) + (gid & 1023)];
        const int n8 = (S_LEN * DDIM) / 8;
        for (int i = gid; i < n8; i += 1024 * 256) {
            float4 a = *(const float4*)(q + (size_t)i * 8);
            float4 b = *(const float4*)(q + (size_t)i * 8 + 4);
            float va[8] = {a.x, a.y, a.z, a.w, b.x, b.y, b.z, b.w};
            bf16x8 h, l;
#pragma unroll
            for (int j = 0; j < 8; ++j) {
                __bf16 hh = (__bf16)va[j];
                h[j] = hh;
                l[j] = (__bf16)(va[j] - (float)hh);
            }
            *(bf16x8*)(qh + (size_t)i * 8) = h;
            *(bf16x8*)(ql + (size_t)i * 8) = l;

            a = *(const float4*)(kk + (size_t)i * 8);
            b = *(const float4*)(kk + (size_t)i * 8 + 4);
            float vb[8] = {a.x, a.y, a.z, a.w, b.x, b.y, b.z, b.w};
#pragma unroll
            for (int j = 0; j < 8; ++j) {
                __bf16 hh = (__bf16)vb[j];
                h[j] = hh;
                l[j] = (__bf16)(vb[j] - (float)hh);
            }
            *(bf16x8*)(kh + (size_t)i * 8) = h;
            *(bf16x8*)(kl + (size_t)i * 8) = l;
        }
    } else {
        const int vbid = bid - 1024;
        const int t0 = (vbid & 127) * 32;
        const int d0 = (vbid >> 7) * 32;
        const int tx = threadIdx.x & 31;
        const int ty = threadIdx.x >> 5;
#pragma unroll
        for (int i = 0; i < 32; i += 8)
            tile[ty + i][tx] = v[(size_t)(t0 + ty + i) * DDIM + d0 + tx];
        __syncthreads();
#pragma unroll
        for (int i = 0; i < 32; i += 8)
            vt[(size_t)(d0 + ty + i) * S_LEN + t0 + tx] = (__bf16)tile[tx][ty + i];
    }
}

// =====================================================================
// G1: S = (Q . K^T) * colscale  (3-term bf16 hi/lo split), 8-phase 256^2
// =====================================================================
__device__ __forceinline__ const __bf16* selA(const __bf16* qh, const __bf16* ql, int ps)
{ return ps == 1 ? ql : qh; }
__device__ __forceinline__ const __bf16* selB(const __bf16* kh, const __bf16* kl, int ps)
{ return ps == 2 ? kl : kh; }

template<int BUF, int RG>
__device__ __forceinline__ void stageG1(__bf16 (&lds)[2][4][8192], const __bf16* pl,
                                        int base, int koff, int w, int lane)
{
#pragma unroll
    for (int j = 0; j < 2; ++j) {
        const int ubase = (2 * w + j) * 64;
        const int u = ubase + lane;
        const int r = u >> 3, cu = u & 7;
        int grow;
        if (RG < 2) grow = base + ((r >> 6) << 7) + ((RG & 1) << 6) + (r & 63);
        else        grow = base + ((r >> 5) << 6) + ((RG & 1) << 5) + (r & 31);
        const __bf16* src = pl + (size_t)grow * DDIM + koff + ((cu ^ (r & 7)) << 3);
        gl_lds16(src, &lds[BUF][RG][0] + ubase * 8);
    }
}

template<int BUF, int MH>
__device__ __forceinline__ void rdA(bf16x8 (&a)[4][2], const __bf16 (&lds)[2][4][8192],
                                    int wr, int arow, int aoct)
{
#pragma unroll
    for (int mi = 0; mi < 4; ++mi)
#pragma unroll
        for (int ks = 0; ks < 2; ++ks) {
            const int lr = wr * 64 + mi * 16 + arow;
            const int cc = ks * 4 + aoct;
            a[mi][ks] = *(const bf16x8*)((const char*)&lds[BUF][MH][0]
                            + lr * 128 + ((cc ^ (lr & 7)) << 4));
        }
}

template<int BUF, int NH>
__device__ __forceinline__ void rdB(bf16x8 (&b)[2][2], const __bf16 (&lds)[2][4][8192],
                                    int wc, int arow, int aoct)
{
#pragma unroll
    for (int ni = 0; ni < 2; ++ni)
#pragma unroll
        for (int ks = 0; ks < 2; ++ks) {
            const int lr = wc * 32 + ni * 16 + arow;
            const int cc = ks * 4 + aoct;
            b[ni][ks] = *(const bf16x8*)((const char*)&lds[BUF][2 + NH][0]
                            + lr * 128 + ((cc ^ (lr & 7)) << 4));
        }
}

#define QMFMA(MH, NH, bb) \
    _Pragma("unroll") for (int ks = 0; ks < 2; ++ks) \
    _Pragma("unroll") for (int mi = 0; mi < 4; ++mi) \
    _Pragma("unroll") for (int ni = 0; ni < 2; ++ni) \
        acc[(MH)*4 + mi][(NH)*2 + ni] = MFMA(a[mi][ks], bb[ni][ks], acc[(MH)*4 + mi][(NH)*2 + ni], 0, 0, 0);

__global__ __launch_bounds__(512, 2) void gemm_qk(
    const __bf16* __restrict__ qh, const __bf16* __restrict__ ql,
    const __bf16* __restrict__ kh, const __bf16* __restrict__ kl,
    const float* __restrict__ scale, float* __restrict__ Sout)
{
    __shared__ __align__(16) __bf16 lds[2][4][8192];   // 128 KB

    const int tid = threadIdx.x;
    const int w = tid >> 6, lane = tid & 63;
    const int arow = lane & 15, aoct = lane >> 4;
    const int wr = w >> 2, wc = w & 3;
    const int nb = (blockIdx.x & 7) * 32 + (blockIdx.x >> 3);
    const int m0 = (nb & 15) * 256, n0 = (nb >> 4) * 256;

    f32x4 acc[8][4];
#pragma unroll
    for (int i = 0; i < 8; ++i)
#pragma unroll
        for (int j = 0; j < 4; ++j) acc[i][j] = (f32x4){0.f, 0.f, 0.f, 0.f};

    stageG1<0, 0>(lds, selA(qh, ql, 0), m0, 0, w, lane);
    stageG1<0, 1>(lds, selA(qh, ql, 0), m0, 0, w, lane);
    stageG1<0, 2>(lds, selB(kh, kl, 0), n0, 0, w, lane);
    stageG1<0, 3>(lds, selB(kh, kl, 0), n0, 0, w, lane);
    stageG1<1, 0>(lds, selA(qh, ql, 0), m0, 64, w, lane);
    stageG1<1, 2>(lds, selB(kh, kl, 0), n0, 64, w, lane);
    stageG1<1, 3>(lds, selB(kh, kl, 0), n0, 64, w, lane);
    VM6(); BAR();

    for (int it = 0; it < 24; ++it) {
        const int t0 = 2 * it, t1 = 2 * it + 1;
        const bool last = (it == 23);
        const int ps1 = t1 >> 4, ko1 = (t1 & 15) << 6;
        const int ps2 = (t0 + 2) >> 4, ko2 = ((t0 + 2) & 15) << 6;
        const int ps3 = (t1 + 2) >> 4, ko3 = ((t1 + 2) & 15) << 6;
        bf16x8 a[4][2], b0[2][2], b1[2][2];

        rdA<0, 0>(a, lds, wr, arow, aoct);
        rdB<0, 0>(b0, lds, wc, arow, aoct);
        stageG1<1, 1>(lds, selA(qh, ql, ps1), m0, ko1, w, lane);
        BAR();
        __builtin_amdgcn_s_setprio(1); QMFMA(0, 0, b0); __builtin_amdgcn_s_setprio(0);
        BAR();
        rdB<0, 1>(b1, lds, wc, arow, aoct);
        if (!last) stageG1<0, 0>(lds, selA(qh, ql, ps2), m0, ko2, w, lane);
        BAR();
        __builtin_amdgcn_s_setprio(1); QMFMA(0, 1, b1); __builtin_amdgcn_s_setprio(0);
        BAR();
        rdA<0, 1>(a, lds, wr, arow, aoct);
        if (!last) stageG1<0, 2>(lds, selB(kh, kl, ps2), n0, ko2, w, lane);
        BAR();
        __builtin_amdgcn_s_setprio(1); QMFMA(1, 0, b0); __builtin_amdgcn_s_setprio(0);
        BAR();
        if (!last) stageG1<0, 3>(lds, selB(kh, kl, ps2), n0, ko2, w, lane);
        if (last) { VM0(); } else { VM6(); }
        BAR();
        __builtin_amdgcn_s_setprio(1); QMFMA(1, 1, b1); __builtin_amdgcn_s_setprio(0);
        BAR();
        rdA<1, 0>(a, lds, wr, arow, aoct);
        rdB<1, 0>(b0, lds, wc, arow, aoct);
        if (!last) stageG1<0, 1>(lds, selA(qh, ql, ps2), m0, ko2, w, lane);
        BAR();
        __builtin_amdgcn_s_setprio(1); QMFMA(0, 0, b0); __builtin_amdgcn_s_setprio(0);
        BAR();
        rdB<1, 1>(b1, lds, wc, arow, aoct);
        if (!last) stageG1<1, 0>(lds, selA(qh, ql, ps3), m0, ko3, w, lane);
        BAR();
        __builtin_amdgcn_s_setprio(1); QMFMA(0, 1, b1); __builtin_amdgcn_s_setprio(0);
        BAR();
        rdA<1, 1>(a, lds, wr, arow, aoct);
        if (!last) stageG1<1, 2>(lds, selB(kh, kl, ps3), n0, ko3, w, lane);
        BAR();
        __builtin_amdgcn_s_setprio(1); QMFMA(1, 0, b0); __builtin_amdgcn_s_setprio(0);
        BAR();
        if (!last) stageG1<1, 3>(lds, selB(kh, kl, ps3), n0, ko3, w, lane);
        if (last) { VM0(); } else { VM6(); }
        BAR();
        __builtin_amdgcn_s_setprio(1); QMFMA(1, 1, b1); __builtin_amdgcn_s_setprio(0);
        BAR();
    }

    // epilogue: apply per-column scale, write fp32 S
    const int nbase = n0 + wc * 64;
    float sc[4];
#pragma unroll
    for (int ni = 0; ni < 4; ++ni) sc[ni] = scale[nbase + ni * 16 + arow];
#pragma unroll
    for (int mi = 0; mi < 8; ++mi)
#pragma unroll
        for (int ni = 0; ni < 4; ++ni)
#pragma unroll
            for (int ii = 0; ii < 4; ++ii) {
                const int m = m0 + wr * 128 + mi * 16 + aoct * 4 + ii;
                Sout[(size_t)m * S_LEN + nbase + ni * 16 + arow] = acc[mi][ni][ii] * sc[ni];
            }
}

// =====================================================================
// softmax: rows of S (fp32) -> normalized bf16 P in-place (pitch 8192)
// =====================================================================
__global__ __launch_bounds__(256) void softmax_kernel(const float* __restrict__ S,
                                                      __bf16* __restrict__ P)
{
    __shared__ float red[8];
    const int row = blockIdx.x, tid = threadIdx.x;
    const int w = tid >> 6, lane = tid & 63;
    const float* sr = S + (size_t)row * S_LEN;
    float4 v[4];
#pragma unroll
    for (int c = 0; c < 4; ++c) v[c] = *(const float4*)(sr + c * 1024 + tid * 4);
    float mx = -3e38f;
#pragma unroll
    for (int c = 0; c < 4; ++c)
        mx = fmaxf(mx, fmaxf(fmaxf(v[c].x, v[c].y), fmaxf(v[c].z, v[c].w)));
#pragma unroll
    for (int sh = 32; sh >= 1; sh >>= 1) mx = fmaxf(mx, __shfl_xor(mx, sh));
    if (lane == 0) red[w] = mx;
    __syncthreads();
    mx = fmaxf(fmaxf(red[0], red[1]), fmaxf(red[2], red[3]));

    float e[4][4];
    float sum = 0.f;
#pragma unroll
    for (int c = 0; c < 4; ++c) {
        e[c][0] = __expf(v[c].x - mx); e[c][1] = __expf(v[c].y - mx);
        e[c][2] = __expf(v[c].z - mx); e[c][3] = __expf(v[c].w - mx);
        sum += (e[c][0] + e[c][1]) + (e[c][2] + e[c][3]);
    }
#pragma unroll
    for (int sh = 32; sh >= 1; sh >>= 1) sum += __shfl_xor(sum, sh);
    if (lane == 0) red[4 + w] = sum;
    __syncthreads();
    sum = (red[4] + red[5]) + (red[6] + red[7]);
    const float inv = 1.f / sum;
#pragma unroll
    for (int c = 0; c < 4; ++c) {
        bf16x4 o = {(__bf16)(e[c][0] * inv), (__bf16)(e[c][1] * inv),
                    (__bf16)(e[c][2] * inv), (__bf16)(e[c][3] * inv)};
        *(bf16x4*)(P + (size_t)row * 8192 + c * 1024 + tid * 4) = o;
    }
}

// =====================================================================
// G2: O = P . V  (A = P bf16 pitch 8192, B^T = vt 1024x4096)
// 128^2 tile, 512 threads, 4-buffer 3-lead counted-vmcnt, two barriers/iter
// =====================================================================
__device__ __forceinline__ void stagePV(__bf16* __restrict__ dst,
                                        const __bf16* __restrict__ P,
                                        const __bf16* __restrict__ vt,
                                        int m0, int n0, int t, int w, int lane)
{
#pragma unroll
    for (int j = 0; j < 2; ++j) {
        const int ubase = (2 * w + j) * 64;
        const int u = ubase + lane;
        const int r = u >> 3, cu = u & 7;
        const int kc = t * 64 + ((cu ^ (r & 7)) << 3);
        gl_lds16(P + (size_t)(m0 + r) * 8192 + kc, dst + ubase * 8);
        gl_lds16(vt + (size_t)(n0 + r) * S_LEN + kc, dst + 8192 + ubase * 8);
    }
}

__global__ __launch_bounds__(512, 1) void gemm_pv(const __bf16* __restrict__ P,
                                                  const __bf16* __restrict__ vt,
                                                  float* __restrict__ out)
{
    __shared__ __align__(16) __bf16 lds[4][2][8192];   // 128 KB, 4-deep

    const int tid = threadIdx.x;
    const int w = tid >> 6, lane = tid & 63;
    const int arow = lane & 15, aoct = lane >> 4;
    const int wr = w >> 2, wc = w & 3;                  // 2M x 4N waves
    const int nb = (blockIdx.x & 7) * 32 + (blockIdx.x >> 3);
    const int m0 = (nb & 31) * 128, n0 = (nb >> 5) * 128;

    f32x4 acc[4][2];
#pragma unroll
    for (int i = 0; i < 4; ++i)
#pragma unroll
        for (int j = 0; j < 2; ++j) acc[i][j] = (f32x4){0.f, 0.f, 0.f, 0.f};

    stagePV(&lds[0][0][0], P, vt, m0, n0, 0, w, lane);
    stagePV(&lds[1][0][0], P, vt, m0, n0, 1, w, lane);
    stagePV(&lds[2][0][0], P, vt, m0, n0, 2, w, lane);
    VM8(); BAR();

    int c0 = 0, c1 = 1, c2 = 2, c3 = 3;
    for (int t = 0; t < 64; ++t) {
        const char* pa = (const char*)&lds[c0][0][0];
        const char* pbv = (const char*)&lds[c0][1][0];
        bf16x8 a[4][2], b[2][2];
#pragma unroll
        for (int mi = 0; mi < 4; ++mi)
#pragma unroll
            for (int ks = 0; ks < 2; ++ks) {
                const int lr = wr * 64 + mi * 16 + arow;
                const int cc = ks * 4 + aoct;
                a[mi][ks] = *(const bf16x8*)(pa + lr * 128 + ((cc ^ (lr & 7)) << 4));
            }
#pragma unroll
        for (int ni = 0; ni < 2; ++ni)
#pragma unroll
            for (int ks = 0; ks < 2; ++ks) {
                const int lr = wc * 32 + ni * 16 + arow;
                const int cc = ks * 4 + aoct;
                b[ni][ks] = *(const bf16x8*)(pbv + lr * 128 + ((cc ^ (lr & 7)) << 4));
            }
        if (t < 61) stagePV(&lds[c3][0][0], P, vt, m0, n0, t + 3, w, lane);
        BAR();
        __builtin_amdgcn_s_setprio(1);
#pragma unroll
        for (int ks = 0; ks < 2; ++ks)
#pragma unroll
            for (int mi = 0; mi < 4; ++mi)
#pragma unroll
                for (int ni = 0; ni < 2; ++ni)
                    acc[mi][ni] = MFMA(a[mi][ks], b[ni][ks], acc[mi][ni], 0, 0, 0);
        __builtin_amdgcn_s_setprio(0);
        __builtin_amdgcn_sched_barrier(0);   // pin MFMAs (and their lgkmcnt) here
        if (t < 61) { VM8(); } else if (t == 61) { VM4(); } else { VM0(); }
        BAR();
        const int tmp = c0; c0 = c1; c1 = c2; c2 = c3; c3 = tmp;
    }

#pragma unroll
    for (int mi = 0; mi < 4; ++mi)
#pragma unroll
        for (int ni = 0; ni < 2; ++ni)
#pragma unroll
            for (int ii = 0; ii < 4; ++ii) {
                const int m = m0 + wr * 64 + mi * 16 + aoct * 4 + ii;
                const int n = n0 + wc * 32 + ni * 16 + arow;
                out[(size_t)m * DDIM + n] = acc[mi][ni][ii];
            }
}

extern "C" void kernel_launch(void* const* d_in, const int* in_sizes, int n_in,
                              void* d_out, int out_size, void* d_ws, size_t ws_size,
                              hipStream_t stream)
{
    const float* q = (const float*)d_in[0];
    const float* k = (const float*)d_in[1];
    const float* v = (const float*)d_in[2];
    float* out = (float*)d_out;

    const size_t PLANE = (size_t)S_LEN * DDIM * sizeof(__bf16);        // 8 MiB
    const size_t SOFF  = 5 * PLANE + 64 * 1024;
    const size_t NEEDED = SOFF + (size_t)S_LEN * S_LEN * sizeof(float); // ~104 MiB
    if (ws_size < NEEDED) return;  // fail visibly (poisoned output)

    char* ws = (char*)d_ws;
    __bf16* qh = (__bf16*)(ws);
    __bf16* ql = (__bf16*)(ws + PLANE);
    __bf16* kh = (__bf16*)(ws + 2 * PLANE);
    __bf16* kl = (__bf16*)(ws + 3 * PLANE);
    __bf16* vt = (__bf16*)(ws + 4 * PLANE);
    float* scale = (float*)(ws + 5 * PLANE);
    float* Smat = (float*)(ws + SOFF);
    __bf16* P = (__bf16*)Smat;   // in-place, row pitch 8192 bf16

    prep_all<<<dim3(5120), dim3(256), 0, stream>>>(q, k, v, qh, ql, kh, kl, vt, scale);
    gemm_qk<<<dim3(256), dim3(512), 0, stream>>>(qh, ql, kh, kl, scale, Smat);
    softmax_kernel<<<dim3(S_LEN), dim3(256), 0, stream>>>(Smat, P);
    gemm_pv<<<dim3(256), dim3(512), 0, stream>>>(P, vt, out);
}

// Round 13
// 159.412 us; speedup vs baseline: 1.2603x; 1.0209x over previous
//
#include <hip/hip_runtime.h>
#include <hip/hip_bf16.h>

typedef __bf16 bf16x8 __attribute__((ext_vector_type(8)));
typedef __bf16 bf16x4 __attribute__((ext_vector_type(4)));
typedef float f32x4 __attribute__((ext_vector_type(4)));

#define S_LEN 4096
#define DDIM  1024

#define MFMA __builtin_amdgcn_mfma_f32_16x16x32_bf16

#define BAR() do { asm volatile("" ::: "memory"); __builtin_amdgcn_s_barrier(); asm volatile("" ::: "memory"); } while (0)
#define VM8() asm volatile("s_waitcnt vmcnt(8)" ::: "memory")
#define VM6() asm volatile("s_waitcnt vmcnt(6)" ::: "memory")
#define VM4() asm volatile("s_waitcnt vmcnt(4)" ::: "memory")
#define VM0() asm volatile("s_waitcnt vmcnt(0)" ::: "memory")

__device__ __forceinline__ void gl_lds16(const __bf16* g, __bf16* l)
{
    __builtin_amdgcn_global_load_lds(
        (const __attribute__((address_space(1))) void*)g,
        (__attribute__((address_space(3))) void*)l, 16, 0, 0);
}

// ---------------- merged prep: hilo+scale (blocks 0..1023) | vt (1024..5119) ----
__global__ void prep_all(const float* __restrict__ q, const float* __restrict__ kk,
                         const float* __restrict__ v,
                         __bf16* __restrict__ qh, __bf16* __restrict__ ql,
                         __bf16* __restrict__ kh, __bf16* __restrict__ kl,
                         __bf16* __restrict__ vt, float* __restrict__ scale)
{
    __shared__ float tile[32][33];
    const int bid = blockIdx.x;
    if (bid < 1024) {
        const int gid = bid * 256 + threadIdx.x;
        if (gid < S_LEN) scale[gid] = q[((size_t)(gid >> 10) << 20) + (gid & 1023)];
        const int n8 = (S_LEN * DDIM) / 8;
        for (int i = gid; i < n8; i += 1024 * 256) {
            float4 a = *(const float4*)(q + (size_t)i * 8);
            float4 b = *(const float4*)(q + (size_t)i * 8 + 4);
            float va[8] = {a.x, a.y, a.z, a.w, b.x, b.y, b.z, b.w};
            bf16x8 h, l;
#pragma unroll
            for (int j = 0; j < 8; ++j) {
                __bf16 hh = (__bf16)va[j];
                h[j] = hh;
                l[j] = (__bf16)(va[j] - (float)hh);
            }
            *(bf16x8*)(qh + (size_t)i * 8) = h;
            *(bf16x8*)(ql + (size_t)i * 8) = l;

            a = *(const float4*)(kk + (size_t)i * 8);
            b = *(const float4*)(kk + (size_t)i * 8 + 4);
            float vb[8] = {a.x, a.y, a.z, a.w, b.x, b.y, b.z, b.w};
#pragma unroll
            for (int j = 0; j < 8; ++j) {
                __bf16 hh = (__bf16)vb[j];
                h[j] = hh;
                l[j] = (__bf16)(vb[j] - (float)hh);
            }
            *(bf16x8*)(kh + (size_t)i * 8) = h;
            *(bf16x8*)(kl + (size_t)i * 8) = l;
        }
    } else {
        const int vbid = bid - 1024;
        const int t0 = (vbid & 127) * 32;
        const int d0 = (vbid >> 7) * 32;
        const int tx = threadIdx.x & 31;
        const int ty = threadIdx.x >> 5;
#pragma unroll
        for (int i = 0; i < 32; i += 8)
            tile[ty + i][tx] = v[(size_t)(t0 + ty + i) * DDIM + d0 + tx];
        __syncthreads();
#pragma unroll
        for (int i = 0; i < 32; i += 8)
            vt[(size_t)(d0 + ty + i) * S_LEN + t0 + tx] = (__bf16)tile[tx][ty + i];
    }
}

// =====================================================================
// G1: S = (Q . K^T) * colscale  (3-term bf16 hi/lo split), 8-phase 256^2
// =====================================================================
__device__ __forceinline__ const __bf16* selA(const __bf16* qh, const __bf16* ql, int ps)
{ return ps == 1 ? ql : qh; }
__device__ __forceinline__ const __bf16* selB(const __bf16* kh, const __bf16* kl, int ps)
{ return ps == 2 ? kl : kh; }

template<int BUF, int RG>
__device__ __forceinline__ void stageG1(__bf16 (&lds)[2][4][8192], const __bf16* pl,
                                        int base, int koff, int w, int lane)
{
#pragma unroll
    for (int j = 0; j < 2; ++j) {
        const int ubase = (2 * w + j) * 64;
        const int u = ubase + lane;
        const int r = u >> 3, cu = u & 7;
        int grow;
        if (RG < 2) grow = base + ((r >> 6) << 7) + ((RG & 1) << 6) + (r & 63);
        else        grow = base + ((r >> 5) << 6) + ((RG & 1) << 5) + (r & 31);
        const __bf16* src = pl + (size_t)grow * DDIM + koff + ((cu ^ (r & 7)) << 3);
        gl_lds16(src, &lds[BUF][RG][0] + ubase * 8);
    }
}

template<int BUF, int MH>
__device__ __forceinline__ void rdA(bf16x8 (&a)[4][2], const __bf16 (&lds)[2][4][8192],
                                    int wr, int arow, int aoct)
{
#pragma unroll
    for (int mi = 0; mi < 4; ++mi)
#pragma unroll
        for (int ks = 0; ks < 2; ++ks) {
            const int lr = wr * 64 + mi * 16 + arow;
            const int cc = ks * 4 + aoct;
            a[mi][ks] = *(const bf16x8*)((const char*)&lds[BUF][MH][0]
                            + lr * 128 + ((cc ^ (lr & 7)) << 4));
        }
}

template<int BUF, int NH>
__device__ __forceinline__ void rdB(bf16x8 (&b)[2][2], const __bf16 (&lds)[2][4][8192],
                                    int wc, int arow, int aoct)
{
#pragma unroll
    for (int ni = 0; ni < 2; ++ni)
#pragma unroll
        for (int ks = 0; ks < 2; ++ks) {
            const int lr = wc * 32 + ni * 16 + arow;
            const int cc = ks * 4 + aoct;
            b[ni][ks] = *(const bf16x8*)((const char*)&lds[BUF][2 + NH][0]
                            + lr * 128 + ((cc ^ (lr & 7)) << 4));
        }
}

#define QMFMA(MH, NH, bb) \
    _Pragma("unroll") for (int ks = 0; ks < 2; ++ks) \
    _Pragma("unroll") for (int mi = 0; mi < 4; ++mi) \
    _Pragma("unroll") for (int ni = 0; ni < 2; ++ni) \
        acc[(MH)*4 + mi][(NH)*2 + ni] = MFMA(a[mi][ks], bb[ni][ks], acc[(MH)*4 + mi][(NH)*2 + ni], 0, 0, 0);

__global__ __launch_bounds__(512, 2) void gemm_qk(
    const __bf16* __restrict__ qh, const __bf16* __restrict__ ql,
    const __bf16* __restrict__ kh, const __bf16* __restrict__ kl,
    const float* __restrict__ scale, float* __restrict__ Sout)
{
    __shared__ __align__(16) __bf16 lds[2][4][8192];   // 128 KB

    const int tid = threadIdx.x;
    const int w = tid >> 6, lane = tid & 63;
    const int arow = lane & 15, aoct = lane >> 4;
    const int wr = w >> 2, wc = w & 3;
    // XCD M-ownership swizzle: xcd = bid&7 owns m-panels {2*xcd, 2*xcd+1}
    // -> per-XCD A working set (qh+ql, 512 rows) = 2MB, L2-resident.
    const int xcd = blockIdx.x & 7, jj = blockIdx.x >> 3;
    const int m0 = (xcd * 2 + (jj & 1)) * 256, n0 = (jj >> 1) * 256;

    f32x4 acc[8][4];
#pragma unroll
    for (int i = 0; i < 8; ++i)
#pragma unroll
        for (int j = 0; j < 4; ++j) acc[i][j] = (f32x4){0.f, 0.f, 0.f, 0.f};

    stageG1<0, 0>(lds, selA(qh, ql, 0), m0, 0, w, lane);
    stageG1<0, 1>(lds, selA(qh, ql, 0), m0, 0, w, lane);
    stageG1<0, 2>(lds, selB(kh, kl, 0), n0, 0, w, lane);
    stageG1<0, 3>(lds, selB(kh, kl, 0), n0, 0, w, lane);
    stageG1<1, 0>(lds, selA(qh, ql, 0), m0, 64, w, lane);
    stageG1<1, 2>(lds, selB(kh, kl, 0), n0, 64, w, lane);
    stageG1<1, 3>(lds, selB(kh, kl, 0), n0, 64, w, lane);
    VM6(); BAR();

    for (int it = 0; it < 24; ++it) {
        const int t0 = 2 * it, t1 = 2 * it + 1;
        const bool last = (it == 23);
        const int ps1 = t1 >> 4, ko1 = (t1 & 15) << 6;
        const int ps2 = (t0 + 2) >> 4, ko2 = ((t0 + 2) & 15) << 6;
        const int ps3 = (t1 + 2) >> 4, ko3 = ((t1 + 2) & 15) << 6;
        bf16x8 a[4][2], b0[2][2], b1[2][2];

        rdA<0, 0>(a, lds, wr, arow, aoct);
        rdB<0, 0>(b0, lds, wc, arow, aoct);
        stageG1<1, 1>(lds, selA(qh, ql, ps1), m0, ko1, w, lane);
        BAR();
        __builtin_amdgcn_s_setprio(1); QMFMA(0, 0, b0); __builtin_amdgcn_s_setprio(0);
        BAR();
        rdB<0, 1>(b1, lds, wc, arow, aoct);
        if (!last) stageG1<0, 0>(lds, selA(qh, ql, ps2), m0, ko2, w, lane);
        BAR();
        __builtin_amdgcn_s_setprio(1); QMFMA(0, 1, b1); __builtin_amdgcn_s_setprio(0);
        BAR();
        rdA<0, 1>(a, lds, wr, arow, aoct);
        if (!last) stageG1<0, 2>(lds, selB(kh, kl, ps2), n0, ko2, w, lane);
        BAR();
        __builtin_amdgcn_s_setprio(1); QMFMA(1, 0, b0); __builtin_amdgcn_s_setprio(0);
        BAR();
        if (!last) stageG1<0, 3>(lds, selB(kh, kl, ps2), n0, ko2, w, lane);
        if (last) { VM0(); } else { VM6(); }
        BAR();
        __builtin_amdgcn_s_setprio(1); QMFMA(1, 1, b1); __builtin_amdgcn_s_setprio(0);
        BAR();
        rdA<1, 0>(a, lds, wr, arow, aoct);
        rdB<1, 0>(b0, lds, wc, arow, aoct);
        if (!last) stageG1<0, 1>(lds, selA(qh, ql, ps2), m0, ko2, w, lane);
        BAR();
        __builtin_amdgcn_s_setprio(1); QMFMA(0, 0, b0); __builtin_amdgcn_s_setprio(0);
        BAR();
        rdB<1, 1>(b1, lds, wc, arow, aoct);
        if (!last) stageG1<1, 0>(lds, selA(qh, ql, ps3), m0, ko3, w, lane);
        BAR();
        __builtin_amdgcn_s_setprio(1); QMFMA(0, 1, b1); __builtin_amdgcn_s_setprio(0);
        BAR();
        rdA<1, 1>(a, lds, wr, arow, aoct);
        if (!last) stageG1<1, 2>(lds, selB(kh, kl, ps3), n0, ko3, w, lane);
        BAR();
        __builtin_amdgcn_s_setprio(1); QMFMA(1, 0, b0); __builtin_amdgcn_s_setprio(0);
        BAR();
        if (!last) stageG1<1, 3>(lds, selB(kh, kl, ps3), n0, ko3, w, lane);
        if (last) { VM0(); } else { VM6(); }
        BAR();
        __builtin_amdgcn_s_setprio(1); QMFMA(1, 1, b1); __builtin_amdgcn_s_setprio(0);
        BAR();
    }

    // epilogue: apply per-column scale, write fp32 S
    const int nbase = n0 + wc * 64;
    float sc[4];
#pragma unroll
    for (int ni = 0; ni < 4; ++ni) sc[ni] = scale[nbase + ni * 16 + arow];
#pragma unroll
    for (int mi = 0; mi < 8; ++mi)
#pragma unroll
        for (int ni = 0; ni < 4; ++ni)
#pragma unroll
            for (int ii = 0; ii < 4; ++ii) {
                const int m = m0 + wr * 128 + mi * 16 + aoct * 4 + ii;
                Sout[(size_t)m * S_LEN + nbase + ni * 16 + arow] = acc[mi][ni][ii] * sc[ni];
            }
}

// =====================================================================
// softmax: rows of S (fp32) -> normalized bf16 P in-place (pitch 8192)
// =====================================================================
__global__ __launch_bounds__(256) void softmax_kernel(const float* __restrict__ S,
                                                      __bf16* __restrict__ P)
{
    __shared__ float red[8];
    const int row = blockIdx.x, tid = threadIdx.x;
    const int w = tid >> 6, lane = tid & 63;
    const float* sr = S + (size_t)row * S_LEN;
    float4 v[4];
#pragma unroll
    for (int c = 0; c < 4; ++c) v[c] = *(const float4*)(sr + c * 1024 + tid * 4);
    float mx = -3e38f;
#pragma unroll
    for (int c = 0; c < 4; ++c)
        mx = fmaxf(mx, fmaxf(fmaxf(v[c].x, v[c].y), fmaxf(v[c].z, v[c].w)));
#pragma unroll
    for (int sh = 32; sh >= 1; sh >>= 1) mx = fmaxf(mx, __shfl_xor(mx, sh));
    if (lane == 0) red[w] = mx;
    __syncthreads();
    mx = fmaxf(fmaxf(red[0], red[1]), fmaxf(red[2], red[3]));

    float e[4][4];
    float sum = 0.f;
#pragma unroll
    for (int c = 0; c < 4; ++c) {
        e[c][0] = __expf(v[c].x - mx); e[c][1] = __expf(v[c].y - mx);
        e[c][2] = __expf(v[c].z - mx); e[c][3] = __expf(v[c].w - mx);
        sum += (e[c][0] + e[c][1]) + (e[c][2] + e[c][3]);
    }
#pragma unroll
    for (int sh = 32; sh >= 1; sh >>= 1) sum += __shfl_xor(sum, sh);
    if (lane == 0) red[4 + w] = sum;
    __syncthreads();
    sum = (red[4] + red[5]) + (red[6] + red[7]);
    const float inv = 1.f / sum;
#pragma unroll
    for (int c = 0; c < 4; ++c) {
        bf16x4 o = {(__bf16)(e[c][0] * inv), (__bf16)(e[c][1] * inv),
                    (__bf16)(e[c][2] * inv), (__bf16)(e[c][3] * inv)};
        *(bf16x4*)(P + (size_t)row * 8192 + c * 1024 + tid * 4) = o;
    }
}

// =====================================================================
// G2: O = P . V  (A = P bf16 pitch 8192, B^T = vt 1024x4096)
// 128^2 tile, 512 threads, 4-buffer 3-lead counted-vmcnt, two barriers/iter
// =====================================================================
__device__ __forceinline__ void stagePV(__bf16* __restrict__ dst,
                                        const __bf16* __restrict__ P,
                                        const __bf16* __restrict__ vt,
                                        int m0, int n0, int t, int w, int lane)
{
#pragma unroll
    for (int j = 0; j < 2; ++j) {
        const int ubase = (2 * w + j) * 64;
        const int u = ubase + lane;
        const int r = u >> 3, cu = u & 7;
        const int kc = t * 64 + ((cu ^ (r & 7)) << 3);
        gl_lds16(P + (size_t)(m0 + r) * 8192 + kc, dst + ubase * 8);
        gl_lds16(vt + (size_t)(n0 + r) * S_LEN + kc, dst + 8192 + ubase * 8);
    }
}

__global__ __launch_bounds__(512, 1) void gemm_pv(const __bf16* __restrict__ P,
                                                  const __bf16* __restrict__ vt,
                                                  float* __restrict__ out)
{
    __shared__ __align__(16) __bf16 lds[4][2][8192];   // 128 KB, 4-deep

    const int tid = threadIdx.x;
    const int w = tid >> 6, lane = tid & 63;
    const int arow = lane & 15, aoct = lane >> 4;
    const int wr = w >> 2, wc = w & 3;                  // 2M x 4N waves
    // XCD M-ownership: xcd owns m-panels {4*xcd .. 4*xcd+3}; P read ~once,
    // vt (8MB) streams via L3 (64MB aggregate) instead of P (256MB).
    const int xcd = blockIdx.x & 7, jj = blockIdx.x >> 3;
    const int m0 = (xcd * 4 + (jj & 3)) * 128, n0 = (jj >> 2) * 128;

    f32x4 acc[4][2];
#pragma unroll
    for (int i = 0; i < 4; ++i)
#pragma unroll
        for (int j = 0; j < 2; ++j) acc[i][j] = (f32x4){0.f, 0.f, 0.f, 0.f};

    stagePV(&lds[0][0][0], P, vt, m0, n0, 0, w, lane);
    stagePV(&lds[1][0][0], P, vt, m0, n0, 1, w, lane);
    stagePV(&lds[2][0][0], P, vt, m0, n0, 2, w, lane);
    VM8(); BAR();

    int c0 = 0, c1 = 1, c2 = 2, c3 = 3;
    for (int t = 0; t < 64; ++t) {
        const char* pa = (const char*)&lds[c0][0][0];
        const char* pbv = (const char*)&lds[c0][1][0];
        bf16x8 a[4][2], b[2][2];
#pragma unroll
        for (int mi = 0; mi < 4; ++mi)
#pragma unroll
            for (int ks = 0; ks < 2; ++ks) {
                const int lr = wr * 64 + mi * 16 + arow;
                const int cc = ks * 4 + aoct;
                a[mi][ks] = *(const bf16x8*)(pa + lr * 128 + ((cc ^ (lr & 7)) << 4));
            }
#pragma unroll
        for (int ni = 0; ni < 2; ++ni)
#pragma unroll
            for (int ks = 0; ks < 2; ++ks) {
                const int lr = wc * 32 + ni * 16 + arow;
                const int cc = ks * 4 + aoct;
                b[ni][ks] = *(const bf16x8*)(pbv + lr * 128 + ((cc ^ (lr & 7)) << 4));
            }
        if (t < 61) stagePV(&lds[c3][0][0], P, vt, m0, n0, t + 3, w, lane);
        BAR();
        __builtin_amdgcn_s_setprio(1);
#pragma unroll
        for (int ks = 0; ks < 2; ++ks)
#pragma unroll
            for (int mi = 0; mi < 4; ++mi)
#pragma unroll
                for (int ni = 0; ni < 2; ++ni)
                    acc[mi][ni] = MFMA(a[mi][ks], b[ni][ks], acc[mi][ni], 0, 0, 0);
        __builtin_amdgcn_s_setprio(0);
        __builtin_amdgcn_sched_barrier(0);   // pin MFMAs (and their lgkmcnt) here
        if (t < 61) { VM8(); } else if (t == 61) { VM4(); } else { VM0(); }
        BAR();
        const int tmp = c0; c0 = c1; c1 = c2; c2 = c3; c3 = tmp;
    }

#pragma unroll
    for (int mi = 0; mi < 4; ++mi)
#pragma unroll
        for (int ni = 0; ni < 2; ++ni)
#pragma unroll
            for (int ii = 0; ii < 4; ++ii) {
                const int m = m0 + wr * 64 + mi * 16 + aoct * 4 + ii;
                const int n = n0 + wc * 32 + ni * 16 + arow;
                out[(size_t)m * DDIM + n] = acc[mi][ni][ii];
            }
}

extern "C" void kernel_launch(void* const* d_in, const int* in_sizes, int n_in,
                              void* d_out, int out_size, void* d_ws, size_t ws_size,
                              hipStream_t stream)
{
    const float* q = (const float*)d_in[0];
    const float* k = (const float*)d_in[1];
    const float* v = (const float*)d_in[2];
    float* out = (float*)d_out;

    const size_t PLANE = (size_t)S_LEN * DDIM * sizeof(__bf16);        // 8 MiB
    const size_t SOFF  = 5 * PLANE + 64 * 1024;
    const size_t NEEDED = SOFF + (size_t)S_LEN * S_LEN * sizeof(float); // ~104 MiB
    if (ws_size < NEEDED) return;  // fail visibly (poisoned output)

    char* ws = (char*)d_ws;
    __bf16* qh = (__bf16*)(ws);
    __bf16* ql = (__bf16*)(ws + PLANE);
    __bf16* kh = (__bf16*)(ws + 2 * PLANE);
    __bf16* kl = (__bf16*)(ws + 3 * PLANE);
    __bf16* vt = (__bf16*)(ws + 4 * PLANE);
    float* scale = (float*)(ws + 5 * PLANE);
    float* Smat = (float*)(ws + SOFF);
    __bf16* P = (__bf16*)Smat;   // in-place, row pitch 8192 bf16

    prep_all<<<dim3(5120), dim3(256), 0, stream>>>(q, k, v, qh, ql, kh, kl, vt, scale);
    gemm_qk<<<dim3(256), dim3(512), 0, stream>>>(qh, ql, kh, kl, scale, Smat);
    softmax_kernel<<<dim3(S_LEN), dim3(256), 0, stream>>>(Smat, P);
    gemm_pv<<<dim3(256), dim3(512), 0, stream>>>(P, vt, out);
}